// Round 11
// baseline (313.160 us; speedup 1.0000x reference)
//
#include <hip/hip_runtime.h>
#include <stdint.h>

#define BB 1024
#define SS 1024
#define TT 20

#define L2 16
#define C2 (SS / L2)  // 64 chunks for backtrack

typedef unsigned uvec2 __attribute__((ext_vector_type(2)));

// Exchange value with lane^32 partner. gfx950 v_permlane32_swap (VALU) if
// available, else bpermute fallback.
__device__ __forceinline__ float swap_half_f(float x, bool lowhalf) {
#if __has_builtin(__builtin_amdgcn_permlane32_swap)
    uvec2 r = __builtin_amdgcn_permlane32_swap(__float_as_uint(x),
                                               __float_as_uint(x), false, false);
    return __uint_as_float(lowhalf ? r.y : r.x);
#else
    return __shfl(x, (int)(threadIdx.x ^ 32), 64);
#endif
}
__device__ __forceinline__ int swap_half_i(int x, bool lowhalf) {
#if __has_builtin(__builtin_amdgcn_permlane32_swap)
    uvec2 r = __builtin_amdgcn_permlane32_swap((unsigned)x, (unsigned)x, false, false);
    return (int)(lowhalf ? r.y : r.x);
#else
    return __shfl(x, (int)(threadIdx.x ^ 32), 64);
#endif
}

// (val,idx) merge for the final-step argmax only.
#define MERGE(vd, id, va, ia, vb, ib)  \
    {                                  \
        bool ge = (va) >= (vb);        \
        vd = ge ? (va) : (vb);         \
        id = ge ? (ia) : (ib);         \
    }

#define RL(x, i) __uint_as_float(__builtin_amdgcn_readlane(__float_as_uint(x), i))

__device__ __forceinline__ void argmax20(
    float c0, float c1, float c2, float c3, float c4, float c5, float c6,
    float c7, float c8, float c9, float c10, float c11, float c12, float c13,
    float c14, float c15, float c16, float c17, float c18, float c19,
    float& best, int& bidx)
{
    float m0, m1, m2, m3, m4, m5, m6, m7, m8, m9;
    int i0, i1, i2, i3, i4, i5, i6, i7, i8, i9;
    MERGE(m0, i0, c0, 0, c1, 1);
    MERGE(m1, i1, c2, 2, c3, 3);
    MERGE(m2, i2, c4, 4, c5, 5);
    MERGE(m3, i3, c6, 6, c7, 7);
    MERGE(m4, i4, c8, 8, c9, 9);
    MERGE(m5, i5, c10, 10, c11, 11);
    MERGE(m6, i6, c12, 12, c13, 13);
    MERGE(m7, i7, c14, 14, c15, 15);
    MERGE(m8, i8, c16, 16, c17, 17);
    MERGE(m9, i9, c18, 18, c19, 19);

    float n0, n1, n2, n3, n4;
    int j0, j1, j2, j3, j4;
    MERGE(n0, j0, m0, i0, m1, i1);
    MERGE(n1, j1, m2, i2, m3, i3);
    MERGE(n2, j2, m4, i4, m5, i5);
    MERGE(n3, j3, m6, i6, m7, i7);
    MERGE(n4, j4, m8, i8, m9, i9);

    float p0, p1;
    int k0, k1;
    MERGE(p0, k0, n0, j0, n1, j1);
    MERGE(p1, k1, n2, j2, n3, j3);

    float q0;
    int l0;
    MERGE(q0, l0, p0, k0, p1, k1);

    MERGE(best, bidx, q0, l0, n4, j4);
}

// ---------------------------------------------------------------------------
// Forward Viterbi: one wave per batch. 2 lane-groups of 10 rows: lanes j
// (0..19) reduce rows 0..9, lanes j+32 reduce rows 10..19. ONE bpermute stage
// + permlane32_swap cross-combine (VALU). Value path = fmax tree (max3);
// backpointer index recovered off the critical path by exact equality scan.
// Unroll-16 emission prefetch (R10-proven).
// ---------------------------------------------------------------------------
__global__ __launch_bounds__(64) void fwd_kernel(
    const float* __restrict__ em,      // [B,S,T]
    const float* __restrict__ startt,  // [T]
    const float* __restrict__ endt,    // [T]
    const float* __restrict__ trans,   // [T,T]
    uint8_t* __restrict__ bp,          // [S,B,T] (s>=1 used)
    int* __restrict__ last_tag)        // [B]
{
    const int b = blockIdx.x;
    const int lane = threadIdx.x;
    const bool lowhalf = lane < 32;
    const int jr = lowhalf ? lane : (lane - 32);
    const int j = (jr < TT) ? jr : (TT - 1);   // column owned (shadows clamp)
    const int rbase = lowhalf ? 0 : 10;        // rows rbase..rbase+9

    // trans column j, rows rbase..rbase+9, in named registers
    const float tr0 = trans[(rbase + 0) * TT + j];
    const float tr1 = trans[(rbase + 1) * TT + j];
    const float tr2 = trans[(rbase + 2) * TT + j];
    const float tr3 = trans[(rbase + 3) * TT + j];
    const float tr4 = trans[(rbase + 4) * TT + j];
    const float tr5 = trans[(rbase + 5) * TT + j];
    const float tr6 = trans[(rbase + 6) * TT + j];
    const float tr7 = trans[(rbase + 7) * TT + j];
    const float tr8 = trans[(rbase + 8) * TT + j];
    const float tr9 = trans[(rbase + 9) * TT + j];

    const float* emb = em + (size_t)b * SS * TT;
    float score = startt[j] + emb[j];  // s = 0 (valid in lanes 0..19; others shadow)

    uint8_t* bpb = bp + (size_t)b * TT + lane;

    // 16 named prefetch registers: f_k holds em[s+k] at body start
    float f0 = emb[(size_t)1 * TT + j],  f1 = emb[(size_t)2 * TT + j];
    float f2 = emb[(size_t)3 * TT + j],  f3 = emb[(size_t)4 * TT + j];
    float f4 = emb[(size_t)5 * TT + j],  f5 = emb[(size_t)6 * TT + j];
    float f6 = emb[(size_t)7 * TT + j],  f7 = emb[(size_t)8 * TT + j];
    float f8 = emb[(size_t)9 * TT + j],  f9 = emb[(size_t)10 * TT + j];
    float f10 = emb[(size_t)11 * TT + j], f11 = emb[(size_t)12 * TT + j];
    float f12 = emb[(size_t)13 * TT + j], f13 = emb[(size_t)14 * TT + j];
    float f14 = emb[(size_t)15 * TT + j], f15 = emb[(size_t)16 * TT + j];

// one Viterbi step at absolute position 'scur' consuming emission FREG
#define VSTEP_CORE(scur, FREG)                                              \
    {                                                                       \
        const float ecur = FREG;                                            \
        const float s0 = __shfl(score, rbase + 0, 64);                      \
        const float s1 = __shfl(score, rbase + 1, 64);                      \
        const float s2 = __shfl(score, rbase + 2, 64);                      \
        const float s3 = __shfl(score, rbase + 3, 64);                      \
        const float s4 = __shfl(score, rbase + 4, 64);                      \
        const float s5 = __shfl(score, rbase + 5, 64);                      \
        const float s6 = __shfl(score, rbase + 6, 64);                      \
        const float s7 = __shfl(score, rbase + 7, 64);                      \
        const float s8 = __shfl(score, rbase + 8, 64);                      \
        const float s9 = __shfl(score, rbase + 9, 64);                      \
        const float c0 = s0 + tr0, c1 = s1 + tr1, c2 = s2 + tr2;            \
        const float c3 = s3 + tr3, c4 = s4 + tr4, c5 = s5 + tr5;            \
        const float c6 = s6 + tr6, c7 = s7 + tr7, c8 = s8 + tr8;            \
        const float c9 = s9 + tr9;                                          \
        /* value path (critical): max3-fused tree, depth 3 */               \
        const float v0 = fmaxf(fmaxf(c0, c1), c2);                          \
        const float v1 = fmaxf(fmaxf(c3, c4), c5);                          \
        const float v2 = fmaxf(fmaxf(c6, c7), c8);                          \
        const float rv = fmaxf(fmaxf(fmaxf(v0, v1), v2), c9);               \
        const float crossv = swap_half_f(rv, lowhalf);                      \
        const float mf = fmaxf(rv, crossv);                                 \
        score = mf + ecur;                                                  \
        /* index path (off critical): exact-equality first-match scan */    \
        unsigned msk = ((c0 == mf) ? 1u : 0u) | ((c1 == mf) ? 2u : 0u) |    \
                       ((c2 == mf) ? 4u : 0u) | ((c3 == mf) ? 8u : 0u) |    \
                       ((c4 == mf) ? 16u : 0u) | ((c5 == mf) ? 32u : 0u) |  \
                       ((c6 == mf) ? 64u : 0u) | ((c7 == mf) ? 128u : 0u) | \
                       ((c8 == mf) ? 256u : 0u) | ((c9 == mf) ? 512u : 0u); \
        const int fm = rbase + __builtin_ctz(msk | 0x80000000u);            \
        const int fmx = swap_half_i(fm, lowhalf);                           \
        const int zf = (fm < fmx) ? fm : fmx;                               \
        if (lane < TT) bpb[(size_t)(scur) * (BB * TT)] = (uint8_t)zf;       \
    }

// step + reload FREG with em[scur+16] (clamped)
#define VSTEP(scur, FREG)                                                   \
    {                                                                       \
        VSTEP_CORE(scur, FREG);                                             \
        const int sn_ = (scur) + 16;                                        \
        const int snc_ = sn_ > (SS - 1) ? (SS - 1) : sn_;                   \
        FREG = emb[(size_t)snc_ * TT + j];                                  \
    }

    // main loop: 63 bodies of 16 steps, s = 1, 17, ..., 993 (steps 1..1008)
    for (int s = 1; s <= SS - 31; s += 16) {
        VSTEP(s + 0, f0);
        VSTEP(s + 1, f1);
        VSTEP(s + 2, f2);
        VSTEP(s + 3, f3);
        VSTEP(s + 4, f4);
        VSTEP(s + 5, f5);
        VSTEP(s + 6, f6);
        VSTEP(s + 7, f7);
        VSTEP(s + 8, f8);
        VSTEP(s + 9, f9);
        VSTEP(s + 10, f10);
        VSTEP(s + 11, f11);
        VSTEP(s + 12, f12);
        VSTEP(s + 13, f13);
        VSTEP(s + 14, f14);
        VSTEP(s + 15, f15);
    }

    // tail: steps 1009..1023; f0..f14 hold em[1009..1023] (loaded, clamped,
    // by the last body). No reloads.
    VSTEP_CORE(SS - 15, f0);
    VSTEP_CORE(SS - 14, f1);
    VSTEP_CORE(SS - 13, f2);
    VSTEP_CORE(SS - 12, f3);
    VSTEP_CORE(SS - 11, f4);
    VSTEP_CORE(SS - 10, f5);
    VSTEP_CORE(SS - 9, f6);
    VSTEP_CORE(SS - 8, f7);
    VSTEP_CORE(SS - 7, f8);
    VSTEP_CORE(SS - 6, f9);
    VSTEP_CORE(SS - 5, f10);
    VSTEP_CORE(SS - 4, f11);
    VSTEP_CORE(SS - 3, f12);
    VSTEP_CORE(SS - 2, f13);
    VSTEP_CORE(SS - 1, f14);

    // final argmax over tags (once; readlane tree from lanes 0..19)
    const float fin = score + endt[j];
    {
        const float g0 = RL(fin, 0), g1 = RL(fin, 1), g2 = RL(fin, 2);
        const float g3 = RL(fin, 3), g4 = RL(fin, 4), g5 = RL(fin, 5);
        const float g6 = RL(fin, 6), g7 = RL(fin, 7), g8 = RL(fin, 8);
        const float g9 = RL(fin, 9), g10 = RL(fin, 10), g11 = RL(fin, 11);
        const float g12 = RL(fin, 12), g13 = RL(fin, 13), g14 = RL(fin, 14);
        const float g15 = RL(fin, 15), g16 = RL(fin, 16), g17 = RL(fin, 17);
        const float g18 = RL(fin, 18), g19 = RL(fin, 19);
        float best;
        int bidx;
        argmax20(g0, g1, g2, g3, g4, g5, g6, g7, g8, g9, g10, g11, g12, g13,
                 g14, g15, g16, g17, g18, g19, best, bidx);
        if (lane == 0) last_tag[b] = bidx;
    }
}

// ---------------------------------------------------------------------------
// Backtrack phase 1: compose per-chunk pointer maps.
// ---------------------------------------------------------------------------
__global__ void bt_compose(const uint8_t* __restrict__ bp, uint8_t* __restrict__ G)
{
    const int tid = blockIdx.x * blockDim.x + threadIdx.x;
    const int total = BB * (C2 - 1) * TT;
    if (tid >= total) return;
    const int j = tid % TT;
    const int r = tid / TT;
    const int c = 1 + (r % (C2 - 1));
    const int b = r / (C2 - 1);

    int t = j;
    const int hi = (c + 1) * L2 - 1;
#pragma unroll
    for (int k = 0; k < L2; ++k) {
        const int s = hi - k;
        t = bp[((size_t)s * BB + b) * TT + t];
    }
    G[((size_t)c * BB + b) * TT + j] = (uint8_t)t;
}

// ---------------------------------------------------------------------------
// Backtrack phase 2: serial scan over chunk boundaries (per batch).
// ---------------------------------------------------------------------------
__global__ void bt_scan(const uint8_t* __restrict__ G,
                        const int* __restrict__ last_tag,
                        int* __restrict__ xtag)
{
    const int b = blockIdx.x * blockDim.x + threadIdx.x;
    if (b >= BB) return;
    int x = last_tag[b];
    xtag[(size_t)(C2 - 1) * BB + b] = x;
    for (int c = C2 - 1; c >= 1; --c) {
        x = G[((size_t)c * BB + b) * TT + x];
        xtag[(size_t)(c - 1) * BB + b] = x;
    }
}

// ---------------------------------------------------------------------------
// Backtrack phase 3: expand within each chunk, write int32 tags.
// ---------------------------------------------------------------------------
__global__ void bt_expand(const uint8_t* __restrict__ bp,
                          const int* __restrict__ xtag,
                          int* __restrict__ out)
{
    const int tid = blockIdx.x * blockDim.x + threadIdx.x;
    if (tid >= BB * C2) return;
    const int c = tid % C2;
    const int b = tid / C2;

    int t = xtag[(size_t)c * BB + b];
    const int hi = (c + 1) * L2 - 1;
    int* ob = out + (size_t)b * SS;
    ob[hi] = t;
#pragma unroll
    for (int k = 0; k < L2 - 1; ++k) {
        const int s = hi - k;
        t = bp[((size_t)s * BB + b) * TT + t];
        ob[s - 1] = t;
    }
}

extern "C" void kernel_launch(void* const* d_in, const int* in_sizes, int n_in,
                              void* d_out, int out_size, void* d_ws, size_t ws_size,
                              hipStream_t stream) {
    const float* em = (const float*)d_in[0];   // emissions [B,S,T]
    const float* st = (const float*)d_in[1];   // start_transitions [T]
    const float* en = (const float*)d_in[2];   // end_transitions [T]
    const float* tr = (const float*)d_in[3];   // transitions [T,T]
    int* out = (int*)d_out;                    // [B,S] int32

    // workspace layout
    const size_t SBT = (size_t)SS * BB * TT;            // 20.97 MB backpointers
    uint8_t* bp = (uint8_t*)d_ws;
    int* last_tag = (int*)((char*)d_ws + SBT);          // 4 KB
    uint8_t* G = (uint8_t*)d_ws + SBT + 4096;           // C2*B*T = 1.31 MB
    int* xtag = (int*)((char*)d_ws + SBT + 4096 + (size_t)C2 * BB * TT);  // 256 KB

    fwd_kernel<<<BB, 64, 0, stream>>>(em, st, en, tr, bp, last_tag);

    const int tot1 = BB * (C2 - 1) * TT;
    bt_compose<<<(tot1 + 255) / 256, 256, 0, stream>>>(bp, G);
    bt_scan<<<(BB + 255) / 256, 256, 0, stream>>>(G, last_tag, xtag);
    bt_expand<<<(BB * C2 + 255) / 256, 256, 0, stream>>>(bp, xtag, out);
}